// Round 14
// baseline (642.224 us; speedup 1.0000x reference)
//
#include <hip/hip_runtime.h>
#include <hip/hip_cooperative_groups.h>
#include <hip/hip_bf16.h>
#include <hip/hip_fp16.h>
#include <math.h>
#include <type_traits>

namespace cg = cooperative_groups;

// ---------------------------------------------------------------------------
// 2-layer GAT (H=1, D=128) on MI355X.
// hs = x @ W_src via fp16 MFMA (16x16x32), stored fp16; al_s/al_d fused into
// the GEMM epilogue. h1 fp16.
// Aggregate: 1 wave/node; 64-lane weight phase then register-fed gather with
// 16 half2 row-loads in flight. (At memory-system roofline: ~460MB/70us.)
// CSR build + weight prep fused into ONE cooperative kernel (grid.sync
// between the 5 bucket-sort phases; prep overlaps the histogram phase).
// ---------------------------------------------------------------------------

#define BKT_SHIFT 8
#define MAX_NB 512
#define EPB 2048

typedef _Float16 half8 __attribute__((ext_vector_type(8)));
typedef float floatx4 __attribute__((ext_vector_type(4)));

// ---- fused prep + CSR build (cooperative) ---------------------------------
__global__ __launch_bounds__(256) void csr_coop_kernel(
    const int* __restrict__ src, const int* __restrict__ dst,
    const float* __restrict__ W1s, const float* __restrict__ a1s,
    const float* __restrict__ W1d, const float* __restrict__ a1d,
    const float* __restrict__ W2s, const float* __restrict__ a2s,
    const float* __restrict__ W2d, const float* __restrict__ a2d,
    __half* __restrict__ wt1, __half* __restrict__ wt2,
    float* __restrict__ wv, int* __restrict__ counts,
    int* __restrict__ totals, int* __restrict__ bbase,
    int* __restrict__ bpack, int* __restrict__ row_ptr,
    int* __restrict__ col, int N, int E, int NB, int NBLK) {
    cg::grid_group grid = cg::this_grid();
    __shared__ int sA[MAX_NB];
    __shared__ int sB[256];
    __shared__ float wtile[32][33];
    const int bid = blockIdx.x;
    const int t = threadIdx.x;

    // ---- phase 0: histogram (blocks < NBLK)  ||  prep (blocks >= NBLK) ----
    if (bid < NBLK) {
        for (int i = t; i < NB; i += 256) sA[i] = 0;
        __syncthreads();
        const int base = bid * EPB;
#pragma unroll
        for (int j = 0; j < EPB / 256; ++j) {
            int i = base + j * 256 + t;
            if (i < E) atomicAdd(&sA[dst[i] >> BKT_SHIFT], 1);
        }
        __syncthreads();
        for (int i = t; i < NB; i += 256)
            counts[(size_t)bid * NB + i] = sA[i];
    } else if (bid < NBLK + 32) {
        const int wb = bid - NBLK;
        const float* W = (wb >> 4) ? W2s : W1s;
        __half* WT = (wb >> 4) ? wt2 : wt1;
        const int sub = wb & 15;
        const int k0 = (sub >> 2) * 32, c0 = (sub & 3) * 32;
        const int r = t >> 5, c = t & 31;
        for (int rr = r; rr < 32; rr += 8)
            wtile[rr][c] = W[(size_t)(k0 + rr) * 128 + c0 + c];
        __syncthreads();
        for (int rr = r; rr < 32; rr += 8)
            WT[(size_t)(c0 + rr) * 128 + k0 + c] = __float2half_rn(wtile[c][rr]);
    } else if (bid < NBLK + 36) {
        if (t < 128) {
            const float* Wt[4] = {W1s, W1d, W2s, W2d};
            const float* at[4] = {a1s, a1d, a2s, a2d};
            const int b = bid - NBLK - 32;
            const float* W = Wt[b];
            const float* a = at[b];
            float s = 0.f;
            for (int d = 0; d < 128; ++d) s += W[t * 128 + d] * a[d];
            wv[b * 128 + t] = s;
        }
    }
    grid.sync();

    // ---- phase 1: per-bucket exclusive scan over blocks (blocks < NB) -----
    if (bid < NB) {
        int v[4];
        const int base = t * 4;
#pragma unroll
        for (int k = 0; k < 4; ++k) {
            int blk = base + k;
            v[k] = (blk < NBLK) ? counts[(size_t)blk * NB + bid] : 0;
        }
        int s = v[0] + v[1] + v[2] + v[3];
        sA[t] = s;
        __syncthreads();
        for (int o = 1; o < 256; o <<= 1) {
            int u = (t >= o) ? sA[t - o] : 0;
            __syncthreads();
            sA[t] += u;
            __syncthreads();
        }
        int run = sA[t] - s;
#pragma unroll
        for (int k = 0; k < 4; ++k) {
            int blk = base + k;
            if (blk < NBLK) counts[(size_t)blk * NB + bid] = run;
            run += v[k];
        }
        if (t == 255) totals[bid] = sA[255];
    }
    grid.sync();

    // ---- phase 2: scan bucket totals -> bases (block 0; 2 entries/thread) -
    if (bid == 0) {
        int v0 = (2 * t < NB) ? totals[2 * t] : 0;
        int v1 = (2 * t + 1 < NB) ? totals[2 * t + 1] : 0;
        int s = v0 + v1;
        sA[t] = s;
        __syncthreads();
        for (int o = 1; o < 256; o <<= 1) {
            int u = (t >= o) ? sA[t - o] : 0;
            __syncthreads();
            sA[t] += u;
            __syncthreads();
        }
        int excl = sA[t] - s;
        if (2 * t < NB) bbase[2 * t] = excl;
        if (2 * t + 1 < NB) bbase[2 * t + 1] = excl + v0;
    }
    grid.sync();

    // ---- phase 3: place packed edges into bucket-grouped array ------------
    if (bid < NBLK) {
        for (int i = t; i < NB; i += 256)
            sA[i] = bbase[i] + counts[(size_t)bid * NB + i];
        __syncthreads();
        const int base = bid * EPB;
#pragma unroll
        for (int j = 0; j < EPB / 256; ++j) {
            int i = base + j * 256 + t;
            if (i < E) {
                int d = dst[i], s = src[i];
                int p = atomicAdd(&sA[d >> BKT_SHIFT], 1);
                bpack[p] = ((d & 255) << 17) | s;
            }
        }
    }
    grid.sync();

    // ---- phase 4: per-bucket row_ptr + col --------------------------------
    if (bid < NB) {
        const int node0 = bid << BKT_SHIFT;
        const int s = bbase[bid];
        const int e = (bid + 1 < NB) ? bbase[bid + 1] : E;
        sA[t] = 0;
        __syncthreads();
        for (int i = s + t; i < e; i += 256) atomicAdd(&sA[bpack[i] >> 17], 1);
        __syncthreads();
        int v = sA[t];
        sB[t] = v;
        __syncthreads();
        for (int o = 1; o < 256; o <<= 1) {
            int u = (t >= o) ? sB[t - o] : 0;
            __syncthreads();
            sB[t] += u;
            __syncthreads();
        }
        int start = sB[t] - v;
        if (node0 + t < N) row_ptr[node0 + t] = s + start;
        __syncthreads();
        sB[t] = s + start;
        __syncthreads();
        for (int i = s + t; i < e; i += 256) {
            int pk = bpack[i];
            int p = atomicAdd(&sB[pk >> 17], 1);
            col[p] = pk & 0x1FFFF;
        }
        if (bid == 0 && t == 0) row_ptr[N] = E;
    }
}

// ---- MFMA GEMM + fused al: C=X@W (fp16), al_s/al_d from staged Xs ---------
template <typename InT>
__global__ __launch_bounds__(256) void gemm_mfma_kernel(
    const InT* __restrict__ X, const __half* __restrict__ WT,
    __half* __restrict__ C, const float* __restrict__ wvs,
    const float* __restrict__ wvd, float* __restrict__ al_s,
    float* __restrict__ al_d, int N) {
    __shared__ __align__(16) __half Ws[128][136];
    __shared__ __align__(16) __half Xs[64][136];
    const int tid = threadIdx.x;
    const int row0 = blockIdx.x * 64;

    {
        int cr = tid >> 1, off = (tid & 1) * 64;
        const __half* srcp = &WT[(size_t)cr * 128 + off];
#pragma unroll
        for (int q = 0; q < 8; ++q)
            *(float4*)&Ws[cr][off + q * 8] = *(const float4*)&srcp[q * 8];
    }
    {
        int xr = tid >> 2, co = (tid & 3) * 32;
        int gr = row0 + xr;
        if constexpr (std::is_same<InT, float>::value) {
#pragma unroll
            for (int q = 0; q < 4; ++q) {
                float4 lo = make_float4(0.f, 0.f, 0.f, 0.f);
                float4 hi = make_float4(0.f, 0.f, 0.f, 0.f);
                if (gr < N) {
                    lo = *(const float4*)&X[(size_t)gr * 128 + co + q * 8];
                    hi = *(const float4*)&X[(size_t)gr * 128 + co + q * 8 + 4];
                }
                __align__(16) __half2 tmp[4];
                tmp[0] = __floats2half2_rn(lo.x, lo.y);
                tmp[1] = __floats2half2_rn(lo.z, lo.w);
                tmp[2] = __floats2half2_rn(hi.x, hi.y);
                tmp[3] = __floats2half2_rn(hi.z, hi.w);
                *(float4*)&Xs[xr][co + q * 8] = *(const float4*)tmp;
            }
        } else {
#pragma unroll
            for (int q = 0; q < 4; ++q) {
                float4 vz = make_float4(0.f, 0.f, 0.f, 0.f);
                if (gr < N)
                    vz = *(const float4*)&X[(size_t)gr * 128 + co + q * 8];
                *(float4*)&Xs[xr][co + q * 8] = vz;
            }
        }
    }
    __syncthreads();

    const int wid = tid >> 6;
    const int lane = tid & 63;
    const int lr = lane & 15, ks = lane >> 4;
    floatx4 acc[8];
#pragma unroll
    for (int t = 0; t < 8; ++t) acc[t] = (floatx4){0.f, 0.f, 0.f, 0.f};

#pragma unroll
    for (int kk = 0; kk < 4; ++kk) {
        half8 a = *(const half8*)&Xs[wid * 16 + lr][kk * 32 + ks * 8];
#pragma unroll
        for (int t = 0; t < 8; ++t) {
            half8 b = *(const half8*)&Ws[t * 16 + lr][kk * 32 + ks * 8];
            acc[t] = __builtin_amdgcn_mfma_f32_16x16x32_f16(a, b, acc[t], 0, 0, 0);
        }
    }
#pragma unroll
    for (int r = 0; r < 4; ++r) {
        int grow = row0 + wid * 16 + ks * 4 + r;
        if (grow < N) {
#pragma unroll
            for (int t = 0; t < 8; ++t)
                C[(size_t)grow * 128 + t * 16 + lr] = __float2half_rn(acc[t][r]);
        }
    }

    // fused al: thread t handles row t>>2, dim-quarter t&3 (32 dims)
    {
        const int r = tid >> 2, q = tid & 3;
        float ps = 0.f, pd = 0.f;
        const int dbase = q * 32;
#pragma unroll
        for (int d = 0; d < 32; ++d) {
            float xv = __half2float(Xs[r][dbase + d]);
            ps = fmaf(xv, wvs[dbase + d], ps);
            pd = fmaf(xv, wvd[dbase + d], pd);
        }
        ps += __shfl_xor(ps, 1); ps += __shfl_xor(ps, 2);
        pd += __shfl_xor(pd, 1); pd += __shfl_xor(pd, 2);
        int gr = row0 + r;
        if (q == 0 && gr < N) { al_s[gr] = ps; al_d[gr] = pd; }
    }
}

// ---- fused aggregate: weight phase in-kernel, 16 gathers in flight --------
template <typename OutT, bool RELU>
__global__ __launch_bounds__(256) void gat_aggregate_fused(
    const __half* __restrict__ hs, const float* __restrict__ al_s,
    const float* __restrict__ al_d, const int* __restrict__ row_ptr,
    const int* __restrict__ col, const float* __restrict__ bias,
    OutT* __restrict__ out, int N) {
    int node = (int)((blockIdx.x * 256u + threadIdx.x) >> 6);
    int lane = threadIdx.x & 63;
    if (node >= N) return;
    const int begin = row_ptr[node], end = row_ptr[node + 1];
    const float ald = al_d[node];
    const int d0 = lane * 2;

    float acc0 = 0.f, acc1 = 0.f, den = 0.f;
    for (int base = begin; base < end; base += 64) {
        const int cnt = min(64, end - base);
        int myidx = 0;
        float w = 0.f;
        if (lane < cnt) {
            myidx = col[base + lane];
            float l = al_s[myidx] + ald;
            l = (l >= 0.f) ? l : 0.2f * l;
            w = __expf(l);
        }
        float ws = w;
#pragma unroll
        for (int o = 32; o >= 1; o >>= 1) ws += __shfl_xor(ws, o);
        den += ws;

        for (int e = 0; e < cnt; e += 16) {
            __half2 v[16];
            float we[16];
#pragma unroll
            for (int j = 0; j < 16; ++j) {
                int s = __shfl(myidx, e + j);
                we[j] = __shfl(w, e + j);
                v[j] = *(const __half2*)&hs[((size_t)(unsigned)s << 7) + d0];
            }
#pragma unroll
            for (int j = 0; j < 16; ++j) {
                float2 f = __half22float2(v[j]);
                acc0 = fmaf(we[j], f.x, acc0);
                acc1 = fmaf(we[j], f.y, acc1);
            }
        }
    }
    const float rden = (den > 0.f) ? 1.f / den : 0.f;
    float o0 = acc0 * rden + bias[d0];
    float o1 = acc1 * rden + bias[d0 + 1];
    if (RELU) { o0 = fmaxf(o0, 0.f); o1 = fmaxf(o1, 0.f); }
    if constexpr (std::is_same<OutT, __half>::value) {
        *(__half2*)&out[(size_t)node * 128 + d0] = __floats2half2_rn(o0, o1);
    } else {
        *(float2*)&out[(size_t)node * 128 + d0] = make_float2(o0, o1);
    }
}

// ---------------------------------------------------------------------------
extern "C" void kernel_launch(void* const* d_in, const int* in_sizes, int n_in,
                              void* d_out, int out_size, void* d_ws,
                              size_t ws_size, hipStream_t stream) {
    const float* x    = (const float*)d_in[0];
    const int*  eidx  = (const int*)d_in[1];
    const float* W1s  = (const float*)d_in[2];
    const float* W1d  = (const float*)d_in[3];
    const float* a1s  = (const float*)d_in[4];
    const float* a1d  = (const float*)d_in[5];
    const float* b1   = (const float*)d_in[6];
    const float* W2s  = (const float*)d_in[7];
    const float* W2d  = (const float*)d_in[8];
    const float* a2s  = (const float*)d_in[9];
    const float* a2d  = (const float*)d_in[10];
    const float* b2   = (const float*)d_in[11];

    int N = in_sizes[0] / 128;
    int E = in_sizes[1] / 2;
    const int* src = eidx;
    const int* dst = eidx + E;

    int NB   = (N + 255) >> BKT_SHIFT;
    int NBLK = (E + EPB - 1) / EPB;

    char* p = (char*)d_ws;
    auto alloc = [&](size_t bytes) {
        char* r = p;
        p += (bytes + 255) & ~(size_t)255;
        return r;
    };
    __half* hsA   = (__half*)alloc((size_t)N * 128 * 2);
    __half* h1    = (__half*)alloc((size_t)N * 128 * 2);
    int*   row_ptr= (int*)alloc((size_t)(N + 1) * 4);
    int*   col    = (int*)alloc((size_t)E * 4);
    int*   bpack  = (int*)alloc((size_t)E * 4);
    int*   counts = (int*)alloc((size_t)NBLK * NB * 4);
    int*   totals = (int*)alloc(MAX_NB * 4);
    int*   bbase  = (int*)alloc(MAX_NB * 4);
    float* al_s   = (float*)alloc((size_t)N * 4);
    float* al_d   = (float*)alloc((size_t)N * 4);
    float* wv     = (float*)alloc(4 * 128 * 4);
    __half* wt1   = (__half*)alloc(128 * 128 * 2);
    __half* wt2   = (__half*)alloc(128 * 128 * 2);

    // fused prep + CSR build (cooperative, grid.sync between phases)
    {
        void* args[] = {(void*)&src,  (void*)&dst,  (void*)&W1s, (void*)&a1s,
                        (void*)&W1d,  (void*)&a1d,  (void*)&W2s, (void*)&a2s,
                        (void*)&W2d,  (void*)&a2d,  (void*)&wt1, (void*)&wt2,
                        (void*)&wv,   (void*)&counts, (void*)&totals,
                        (void*)&bbase, (void*)&bpack, (void*)&row_ptr,
                        (void*)&col,  (void*)&N,    (void*)&E,   (void*)&NB,
                        (void*)&NBLK};
        hipLaunchCooperativeKernel((const void*)csr_coop_kernel,
                                   dim3(NBLK + 36), dim3(256), args, 0,
                                   stream);
    }

    const int gemm_grid = (N + 63) / 64;
    const int wave_grid = (N + 3) / 4;

    // ---- layer 1 ----
    gemm_mfma_kernel<float><<<gemm_grid, 256, 0, stream>>>(
        x, wt1, hsA, wv + 0, wv + 128, al_s, al_d, N);
    gat_aggregate_fused<__half, true><<<wave_grid, 256, 0, stream>>>(
        hsA, al_s, al_d, row_ptr, col, b1, h1, N);

    // ---- layer 2 ----
    gemm_mfma_kernel<__half><<<gemm_grid, 256, 0, stream>>>(
        h1, wt2, hsA, wv + 256, wv + 384, al_s, al_d, N);
    gat_aggregate_fused<float, false><<<wave_grid, 256, 0, stream>>>(
        hsA, al_s, al_d, row_ptr, col, b2, (float*)d_out, N);
}

// Round 15
// 266.061 us; speedup vs baseline: 2.4138x; 2.4138x over previous
//
#include <hip/hip_runtime.h>
#include <hip/hip_bf16.h>
#include <hip/hip_fp16.h>
#include <math.h>
#include <type_traits>

// ---------------------------------------------------------------------------
// 2-layer GAT (H=1, D=128) on MI355X.
// hs = x @ W_src via fp16 MFMA (16x16x32), stored fp16; al_s/al_d fused into
// the GEMM epilogue. h1 fp16.
// Aggregate: 1 wave/node; 64-lane weight phase then register-fed gather with
// 16 half2 row-loads in flight. (~460MB/70us: memory-system roofline.)
// CSR build, 4 launches, no inter-block prefix array:
//   A: per-block LDS hist -> atomicAdd into totals[NB]   (+prep rides along)
//   B: 1-block scan totals -> bbase + global cursors
//   C: edges in registers; block reserves bucket windows via atomicAdd on
//      cursors; LDS-cursor placement of packed (dst&255)<<17|src
//   D: per-bucket row_ptr + col (unchanged)
// ---------------------------------------------------------------------------

#define BKT_SHIFT 8
#define MAX_NB 512
#define EPB 2048

typedef _Float16 half8 __attribute__((ext_vector_type(8)));
typedef float floatx4 __attribute__((ext_vector_type(4)));

// ---- pass A: bucket histogram -> global totals; prep in extra blocks ------
__global__ __launch_bounds__(256) void bucket_hist_prep_kernel(
    const int* __restrict__ dst, int* __restrict__ totals,
    const float* __restrict__ W1s, const float* __restrict__ a1s,
    const float* __restrict__ W1d, const float* __restrict__ a1d,
    const float* __restrict__ W2s, const float* __restrict__ a2s,
    const float* __restrict__ W2d, const float* __restrict__ a2d,
    __half* __restrict__ wt1, __half* __restrict__ wt2,
    float* __restrict__ wv, int E, int NB, int NBLK) {
    const int bid = blockIdx.x;
    const int t = threadIdx.x;
    if (bid < NBLK) {
        __shared__ int h[MAX_NB];
        for (int i = t; i < NB; i += 256) h[i] = 0;
        __syncthreads();
        const int base = bid * EPB;
#pragma unroll
        for (int j = 0; j < EPB / 256; ++j) {
            int i = base + j * 256 + t;
            if (i < E) atomicAdd(&h[dst[i] >> BKT_SHIFT], 1);
        }
        __syncthreads();
        for (int i = t; i < NB; i += 256)
            if (h[i] > 0) atomicAdd(&totals[i], h[i]);
    } else if (bid < NBLK + 32) {
        __shared__ float wtile[32][33];
        const int wb = bid - NBLK;
        const float* W = (wb >> 4) ? W2s : W1s;
        __half* WT = (wb >> 4) ? wt2 : wt1;
        const int sub = wb & 15;
        const int k0 = (sub >> 2) * 32, c0 = (sub & 3) * 32;
        const int r = t >> 5, c = t & 31;
        for (int rr = r; rr < 32; rr += 8)
            wtile[rr][c] = W[(size_t)(k0 + rr) * 128 + c0 + c];
        __syncthreads();
        for (int rr = r; rr < 32; rr += 8)
            WT[(size_t)(c0 + rr) * 128 + k0 + c] = __float2half_rn(wtile[c][rr]);
    } else {
        if (t < 128) {
            const float* Wt[4] = {W1s, W1d, W2s, W2d};
            const float* at[4] = {a1s, a1d, a2s, a2d};
            const int b = bid - NBLK - 32;
            const float* W = Wt[b];
            const float* a = at[b];
            float s = 0.f;
            for (int d = 0; d < 128; ++d) s += W[t * 128 + d] * a[d];
            wv[b * 128 + t] = s;
        }
    }
}

// ---- pass B: 1-block scan of totals -> bbase + cursors --------------------
__global__ void bucket_base_kernel(const int* __restrict__ totals,
                                   int* __restrict__ bbase,
                                   int* __restrict__ gcur, int NB) {
    __shared__ int sh[MAX_NB];
    int t = threadIdx.x;  // 512
    int v = (t < NB) ? totals[t] : 0;
    sh[t] = v;
    __syncthreads();
    for (int o = 1; o < MAX_NB; o <<= 1) {
        int u = (t >= o) ? sh[t - o] : 0;
        __syncthreads();
        sh[t] += u;
        __syncthreads();
    }
    if (t < NB) {
        int excl = sh[t] - v;
        bbase[t] = excl;
        gcur[t] = excl;
    }
}

// ---- pass C: reserve windows via cursor atomics; place packed edges -------
__global__ __launch_bounds__(256) void bucket_place_kernel(
    const int* __restrict__ src, const int* __restrict__ dst,
    int* __restrict__ gcur, int* __restrict__ bpack, int E, int NB) {
    __shared__ int h[MAX_NB];
    const int bid = blockIdx.x;
    const int t = threadIdx.x;
    const int base = bid * EPB;
    int d[8], s[8];
    bool ok[8];
#pragma unroll
    for (int j = 0; j < 8; ++j) {
        int i = base + j * 256 + t;
        ok[j] = (i < E);
        d[j] = ok[j] ? dst[i] : 0;
        s[j] = ok[j] ? src[i] : 0;
    }
    for (int i = t; i < NB; i += 256) h[i] = 0;
    __syncthreads();
#pragma unroll
    for (int j = 0; j < 8; ++j)
        if (ok[j]) atomicAdd(&h[d[j] >> BKT_SHIFT], 1);
    __syncthreads();
    // reserve a contiguous window per non-empty bucket
    for (int i = t; i < NB; i += 256) {
        int c = h[i];
        if (c > 0) h[i] = atomicAdd(&gcur[i], c);
    }
    __syncthreads();
#pragma unroll
    for (int j = 0; j < 8; ++j) {
        if (ok[j]) {
            int p = atomicAdd(&h[d[j] >> BKT_SHIFT], 1);
            bpack[p] = ((d[j] & 255) << 17) | s[j];
        }
    }
}

// ---- pass D: per-bucket row_ptr + col -------------------------------------
__global__ void bucket_csr_kernel(const int* __restrict__ bpack,
                                  const int* __restrict__ bbase,
                                  int* __restrict__ row_ptr,
                                  int* __restrict__ col, int N, int E,
                                  int NB) {
    __shared__ int cnt[256];
    __shared__ int cur[256];
    const int b = blockIdx.x;
    const int t = threadIdx.x;
    const int node0 = b << BKT_SHIFT;
    const int s = bbase[b];
    const int e = (b + 1 < NB) ? bbase[b + 1] : E;
    cnt[t] = 0;
    __syncthreads();
    for (int i = s + t; i < e; i += 256) atomicAdd(&cnt[bpack[i] >> 17], 1);
    __syncthreads();
    int v = cnt[t];
    cur[t] = v;
    __syncthreads();
    for (int o = 1; o < 256; o <<= 1) {
        int u = (t >= o) ? cur[t - o] : 0;
        __syncthreads();
        cur[t] += u;
        __syncthreads();
    }
    int start = cur[t] - v;
    if (node0 + t < N) row_ptr[node0 + t] = s + start;
    __syncthreads();
    cur[t] = s + start;
    __syncthreads();
    for (int i = s + t; i < e; i += 256) {
        int pk = bpack[i];
        int p = atomicAdd(&cur[pk >> 17], 1);
        col[p] = pk & 0x1FFFF;
    }
    if (b == 0 && t == 0) row_ptr[N] = E;
}

// ---- MFMA GEMM + fused al: C=X@W (fp16), al_s/al_d from staged Xs ---------
template <typename InT>
__global__ __launch_bounds__(256) void gemm_mfma_kernel(
    const InT* __restrict__ X, const __half* __restrict__ WT,
    __half* __restrict__ C, const float* __restrict__ wvs,
    const float* __restrict__ wvd, float* __restrict__ al_s,
    float* __restrict__ al_d, int N) {
    __shared__ __align__(16) __half Ws[128][136];
    __shared__ __align__(16) __half Xs[64][136];
    const int tid = threadIdx.x;
    const int row0 = blockIdx.x * 64;

    {
        int cr = tid >> 1, off = (tid & 1) * 64;
        const __half* srcp = &WT[(size_t)cr * 128 + off];
#pragma unroll
        for (int q = 0; q < 8; ++q)
            *(float4*)&Ws[cr][off + q * 8] = *(const float4*)&srcp[q * 8];
    }
    {
        int xr = tid >> 2, co = (tid & 3) * 32;
        int gr = row0 + xr;
        if constexpr (std::is_same<InT, float>::value) {
#pragma unroll
            for (int q = 0; q < 4; ++q) {
                float4 lo = make_float4(0.f, 0.f, 0.f, 0.f);
                float4 hi = make_float4(0.f, 0.f, 0.f, 0.f);
                if (gr < N) {
                    lo = *(const float4*)&X[(size_t)gr * 128 + co + q * 8];
                    hi = *(const float4*)&X[(size_t)gr * 128 + co + q * 8 + 4];
                }
                __align__(16) __half2 tmp[4];
                tmp[0] = __floats2half2_rn(lo.x, lo.y);
                tmp[1] = __floats2half2_rn(lo.z, lo.w);
                tmp[2] = __floats2half2_rn(hi.x, hi.y);
                tmp[3] = __floats2half2_rn(hi.z, hi.w);
                *(float4*)&Xs[xr][co + q * 8] = *(const float4*)tmp;
            }
        } else {
#pragma unroll
            for (int q = 0; q < 4; ++q) {
                float4 vz = make_float4(0.f, 0.f, 0.f, 0.f);
                if (gr < N)
                    vz = *(const float4*)&X[(size_t)gr * 128 + co + q * 8];
                *(float4*)&Xs[xr][co + q * 8] = vz;
            }
        }
    }
    __syncthreads();

    const int wid = tid >> 6;
    const int lane = tid & 63;
    const int lr = lane & 15, ks = lane >> 4;
    floatx4 acc[8];
#pragma unroll
    for (int t = 0; t < 8; ++t) acc[t] = (floatx4){0.f, 0.f, 0.f, 0.f};

#pragma unroll
    for (int kk = 0; kk < 4; ++kk) {
        half8 a = *(const half8*)&Xs[wid * 16 + lr][kk * 32 + ks * 8];
#pragma unroll
        for (int t = 0; t < 8; ++t) {
            half8 b = *(const half8*)&Ws[t * 16 + lr][kk * 32 + ks * 8];
            acc[t] = __builtin_amdgcn_mfma_f32_16x16x32_f16(a, b, acc[t], 0, 0, 0);
        }
    }
#pragma unroll
    for (int r = 0; r < 4; ++r) {
        int grow = row0 + wid * 16 + ks * 4 + r;
        if (grow < N) {
#pragma unroll
            for (int t = 0; t < 8; ++t)
                C[(size_t)grow * 128 + t * 16 + lr] = __float2half_rn(acc[t][r]);
        }
    }

    // fused al: thread t handles row t>>2, dim-quarter t&3 (32 dims)
    {
        const int r = tid >> 2, q = tid & 3;
        float ps = 0.f, pd = 0.f;
        const int dbase = q * 32;
#pragma unroll
        for (int d = 0; d < 32; ++d) {
            float xv = __half2float(Xs[r][dbase + d]);
            ps = fmaf(xv, wvs[dbase + d], ps);
            pd = fmaf(xv, wvd[dbase + d], pd);
        }
        ps += __shfl_xor(ps, 1); ps += __shfl_xor(ps, 2);
        pd += __shfl_xor(pd, 1); pd += __shfl_xor(pd, 2);
        int gr = row0 + r;
        if (q == 0 && gr < N) { al_s[gr] = ps; al_d[gr] = pd; }
    }
}

// ---- fused aggregate: weight phase in-kernel, 16 gathers in flight --------
template <typename OutT, bool RELU>
__global__ __launch_bounds__(256) void gat_aggregate_fused(
    const __half* __restrict__ hs, const float* __restrict__ al_s,
    const float* __restrict__ al_d, const int* __restrict__ row_ptr,
    const int* __restrict__ col, const float* __restrict__ bias,
    OutT* __restrict__ out, int N) {
    int node = (int)((blockIdx.x * 256u + threadIdx.x) >> 6);
    int lane = threadIdx.x & 63;
    if (node >= N) return;
    const int begin = row_ptr[node], end = row_ptr[node + 1];
    const float ald = al_d[node];
    const int d0 = lane * 2;

    float acc0 = 0.f, acc1 = 0.f, den = 0.f;
    for (int base = begin; base < end; base += 64) {
        const int cnt = min(64, end - base);
        int myidx = 0;
        float w = 0.f;
        if (lane < cnt) {
            myidx = col[base + lane];
            float l = al_s[myidx] + ald;
            l = (l >= 0.f) ? l : 0.2f * l;
            w = __expf(l);
        }
        float ws = w;
#pragma unroll
        for (int o = 32; o >= 1; o >>= 1) ws += __shfl_xor(ws, o);
        den += ws;

        for (int e = 0; e < cnt; e += 16) {
            __half2 v[16];
            float we[16];
#pragma unroll
            for (int j = 0; j < 16; ++j) {
                int s = __shfl(myidx, e + j);
                we[j] = __shfl(w, e + j);
                v[j] = *(const __half2*)&hs[((size_t)(unsigned)s << 7) + d0];
            }
#pragma unroll
            for (int j = 0; j < 16; ++j) {
                float2 f = __half22float2(v[j]);
                acc0 = fmaf(we[j], f.x, acc0);
                acc1 = fmaf(we[j], f.y, acc1);
            }
        }
    }
    const float rden = (den > 0.f) ? 1.f / den : 0.f;
    float o0 = acc0 * rden + bias[d0];
    float o1 = acc1 * rden + bias[d0 + 1];
    if (RELU) { o0 = fmaxf(o0, 0.f); o1 = fmaxf(o1, 0.f); }
    if constexpr (std::is_same<OutT, __half>::value) {
        *(__half2*)&out[(size_t)node * 128 + d0] = __floats2half2_rn(o0, o1);
    } else {
        *(float2*)&out[(size_t)node * 128 + d0] = make_float2(o0, o1);
    }
}

// ---------------------------------------------------------------------------
extern "C" void kernel_launch(void* const* d_in, const int* in_sizes, int n_in,
                              void* d_out, int out_size, void* d_ws,
                              size_t ws_size, hipStream_t stream) {
    const float* x    = (const float*)d_in[0];
    const int*  eidx  = (const int*)d_in[1];
    const float* W1s  = (const float*)d_in[2];
    const float* W1d  = (const float*)d_in[3];
    const float* a1s  = (const float*)d_in[4];
    const float* a1d  = (const float*)d_in[5];
    const float* b1   = (const float*)d_in[6];
    const float* W2s  = (const float*)d_in[7];
    const float* W2d  = (const float*)d_in[8];
    const float* a2s  = (const float*)d_in[9];
    const float* a2d  = (const float*)d_in[10];
    const float* b2   = (const float*)d_in[11];

    const int N = in_sizes[0] / 128;
    const int E = in_sizes[1] / 2;
    const int* src = eidx;
    const int* dst = eidx + E;

    const int NB   = (N + 255) >> BKT_SHIFT;
    const int NBLK = (E + EPB - 1) / EPB;

    char* p = (char*)d_ws;
    auto alloc = [&](size_t bytes) {
        char* r = p;
        p += (bytes + 255) & ~(size_t)255;
        return r;
    };
    __half* hsA   = (__half*)alloc((size_t)N * 128 * 2);
    __half* h1    = (__half*)alloc((size_t)N * 128 * 2);
    int*   row_ptr= (int*)alloc((size_t)(N + 1) * 4);
    int*   col    = (int*)alloc((size_t)E * 4);
    int*   bpack  = (int*)alloc((size_t)E * 4);
    int*   totals = (int*)alloc(MAX_NB * 4);
    int*   bbase  = (int*)alloc(MAX_NB * 4);
    int*   gcur   = (int*)alloc(MAX_NB * 4);
    float* al_s   = (float*)alloc((size_t)N * 4);
    float* al_d   = (float*)alloc((size_t)N * 4);
    float* wv     = (float*)alloc(4 * 128 * 4);
    __half* wt1   = (__half*)alloc(128 * 128 * 2);
    __half* wt2   = (__half*)alloc(128 * 128 * 2);

    // ---- CSR build (4 launches) + prep ----
    hipMemsetAsync(totals, 0, (size_t)NB * 4, stream);
    bucket_hist_prep_kernel<<<NBLK + 36, 256, 0, stream>>>(
        dst, totals, W1s, a1s, W1d, a1d, W2s, a2s, W2d, a2d, wt1, wt2, wv, E,
        NB, NBLK);
    bucket_base_kernel<<<1, MAX_NB, 0, stream>>>(totals, bbase, gcur, NB);
    bucket_place_kernel<<<NBLK, 256, 0, stream>>>(src, dst, gcur, bpack, E,
                                                  NB);
    bucket_csr_kernel<<<NB, 256, 0, stream>>>(bpack, bbase, row_ptr, col, N, E,
                                              NB);

    const int gemm_grid = (N + 63) / 64;
    const int wave_grid = (N + 3) / 4;

    // ---- layer 1 ----
    gemm_mfma_kernel<float><<<gemm_grid, 256, 0, stream>>>(
        x, wt1, hsA, wv + 0, wv + 128, al_s, al_d, N);
    gat_aggregate_fused<__half, true><<<wave_grid, 256, 0, stream>>>(
        hsA, al_s, al_d, row_ptr, col, b1, h1, N);

    // ---- layer 2 ----
    gemm_mfma_kernel<__half><<<gemm_grid, 256, 0, stream>>>(
        h1, wt2, hsA, wv + 256, wv + 384, al_s, al_d, N);
    gat_aggregate_fused<float, false><<<wave_grid, 256, 0, stream>>>(
        hsA, al_s, al_d, row_ptr, col, b2, (float*)d_out, N);
}

// Round 16
// 241.775 us; speedup vs baseline: 2.6563x; 1.1004x over previous
//
#include <hip/hip_runtime.h>
#include <hip/hip_bf16.h>
#include <hip/hip_fp16.h>
#include <math.h>
#include <type_traits>

// ---------------------------------------------------------------------------
// 2-layer GAT (H=1, D=128) on MI355X.  [r13 structure, prep merged into
// the histogram launch]
// hs = x @ W_src via fp16 MFMA (16x16x32), stored fp16; al_s/al_d fused into
// the GEMM epilogue. h1 fp16.
// Aggregate: 1 wave/node; 64-lane weight phase then register-fed gather with
// 16 half2 row-loads in flight. (~460MB/70us: memory-system roofline.)
// CSR by 2-level LDS bucket sort with distributed counts[NBLK][NB] prefix
// (no hot-line atomics), packed pass C.
// ---------------------------------------------------------------------------

#define BKT_SHIFT 8
#define MAX_NB 512
#define EPB 2048

typedef _Float16 half8 __attribute__((ext_vector_type(8)));
typedef float floatx4 __attribute__((ext_vector_type(4)));

// ---- pass A: per-block bucket histogram; prep rides along -----------------
__global__ __launch_bounds__(256) void bucket_count_prep_kernel(
    const int* __restrict__ dst, int* __restrict__ counts,
    const float* __restrict__ W1s, const float* __restrict__ a1s,
    const float* __restrict__ W1d, const float* __restrict__ a1d,
    const float* __restrict__ W2s, const float* __restrict__ a2s,
    const float* __restrict__ W2d, const float* __restrict__ a2d,
    __half* __restrict__ wt1, __half* __restrict__ wt2,
    float* __restrict__ wv, int E, int NB, int NBLK) {
    const int bid = blockIdx.x;
    const int t = threadIdx.x;
    if (bid < NBLK) {
        __shared__ int h[MAX_NB];
        for (int i = t; i < NB; i += 256) h[i] = 0;
        __syncthreads();
        const int base = bid * EPB;
#pragma unroll
        for (int j = 0; j < EPB / 256; ++j) {
            int i = base + j * 256 + t;
            if (i < E) atomicAdd(&h[dst[i] >> BKT_SHIFT], 1);
        }
        __syncthreads();
        for (int i = t; i < NB; i += 256)
            counts[(size_t)bid * NB + i] = h[i];
    } else if (bid < NBLK + 32) {
        __shared__ float wtile[32][33];
        const int wb = bid - NBLK;
        const float* W = (wb >> 4) ? W2s : W1s;
        __half* WT = (wb >> 4) ? wt2 : wt1;
        const int sub = wb & 15;
        const int k0 = (sub >> 2) * 32, c0 = (sub & 3) * 32;
        const int r = t >> 5, c = t & 31;
        for (int rr = r; rr < 32; rr += 8)
            wtile[rr][c] = W[(size_t)(k0 + rr) * 128 + c0 + c];
        __syncthreads();
        for (int rr = r; rr < 32; rr += 8)
            WT[(size_t)(c0 + rr) * 128 + k0 + c] = __float2half_rn(wtile[c][rr]);
    } else {
        if (t < 128) {
            const float* Wt[4] = {W1s, W1d, W2s, W2d};
            const float* at[4] = {a1s, a1d, a2s, a2d};
            const int b = bid - NBLK - 32;
            const float* W = Wt[b];
            const float* a = at[b];
            float s = 0.f;
            for (int d = 0; d < 128; ++d) s += W[t * 128 + d] * a[d];
            wv[b * 128 + t] = s;
        }
    }
}

// ---- pass B3: per-bucket exclusive scan over blocks + totals --------------
__global__ void bucket_prefix_kernel(int* __restrict__ counts,
                                     int* __restrict__ totals, int NBLK,
                                     int NB) {
    __shared__ int lsum[256];
    const int b = blockIdx.x;
    const int t = threadIdx.x;
    int v[4];
    const int base = t * 4;
#pragma unroll
    for (int k = 0; k < 4; ++k) {
        int blk = base + k;
        v[k] = (blk < NBLK) ? counts[(size_t)blk * NB + b] : 0;
    }
    int s = v[0] + v[1] + v[2] + v[3];
    lsum[t] = s;
    __syncthreads();
    for (int o = 1; o < 256; o <<= 1) {
        int u = (t >= o) ? lsum[t - o] : 0;
        __syncthreads();
        lsum[t] += u;
        __syncthreads();
    }
    int run = lsum[t] - s;
#pragma unroll
    for (int k = 0; k < 4; ++k) {
        int blk = base + k;
        if (blk < NBLK) counts[(size_t)blk * NB + b] = run;
        run += v[k];
    }
    if (t == 255) totals[b] = lsum[255];
}

// ---- pass B2: exclusive scan of bucket totals -> bases --------------------
__global__ void bucket_base_kernel(const int* __restrict__ totals,
                                   int* __restrict__ bbase, int NB) {
    __shared__ int sh[MAX_NB];
    int t = threadIdx.x;
    int v = (t < NB) ? totals[t] : 0;
    sh[t] = v;
    __syncthreads();
    for (int o = 1; o < MAX_NB; o <<= 1) {
        int u = (t >= o) ? sh[t - o] : 0;
        __syncthreads();
        sh[t] += u;
        __syncthreads();
    }
    if (t < NB) bbase[t] = sh[t] - v;
}

// ---- pass C: place packed edges via LDS cursors (from counts+bbase) -------
__global__ void bucket_place_kernel(const int* __restrict__ src,
                                    const int* __restrict__ dst,
                                    const int* __restrict__ prefix,
                                    const int* __restrict__ bbase,
                                    int* __restrict__ bpack, int E, int NB) {
    __shared__ int cur[MAX_NB];
    const int blk = blockIdx.x;
    for (int i = threadIdx.x; i < NB; i += 256)
        cur[i] = bbase[i] + prefix[(size_t)blk * NB + i];
    __syncthreads();
    const int base = blk * EPB;
#pragma unroll
    for (int j = 0; j < EPB / 256; ++j) {
        int i = base + j * 256 + threadIdx.x;
        if (i < E) {
            int d = dst[i], s = src[i];
            int p = atomicAdd(&cur[d >> BKT_SHIFT], 1);
            bpack[p] = ((d & 255) << 17) | s;
        }
    }
}

// ---- pass D: per-bucket row_ptr + col -------------------------------------
__global__ void bucket_csr_kernel(const int* __restrict__ bpack,
                                  const int* __restrict__ bbase,
                                  int* __restrict__ row_ptr,
                                  int* __restrict__ col, int N, int E,
                                  int NB) {
    __shared__ int cnt[256];
    __shared__ int cur[256];
    const int b = blockIdx.x;
    const int t = threadIdx.x;
    const int node0 = b << BKT_SHIFT;
    const int s = bbase[b];
    const int e = (b + 1 < NB) ? bbase[b + 1] : E;
    cnt[t] = 0;
    __syncthreads();
    for (int i = s + t; i < e; i += 256) atomicAdd(&cnt[bpack[i] >> 17], 1);
    __syncthreads();
    int v = cnt[t];
    cur[t] = v;
    __syncthreads();
    for (int o = 1; o < 256; o <<= 1) {
        int u = (t >= o) ? cur[t - o] : 0;
        __syncthreads();
        cur[t] += u;
        __syncthreads();
    }
    int start = cur[t] - v;
    if (node0 + t < N) row_ptr[node0 + t] = s + start;
    __syncthreads();
    cur[t] = s + start;
    __syncthreads();
    for (int i = s + t; i < e; i += 256) {
        int pk = bpack[i];
        int p = atomicAdd(&cur[pk >> 17], 1);
        col[p] = pk & 0x1FFFF;
    }
    if (b == 0 && t == 0) row_ptr[N] = E;
}

// ---- MFMA GEMM + fused al: C=X@W (fp16), al_s/al_d from staged Xs ---------
template <typename InT>
__global__ __launch_bounds__(256) void gemm_mfma_kernel(
    const InT* __restrict__ X, const __half* __restrict__ WT,
    __half* __restrict__ C, const float* __restrict__ wvs,
    const float* __restrict__ wvd, float* __restrict__ al_s,
    float* __restrict__ al_d, int N) {
    __shared__ __align__(16) __half Ws[128][136];
    __shared__ __align__(16) __half Xs[64][136];
    const int tid = threadIdx.x;
    const int row0 = blockIdx.x * 64;

    {
        int cr = tid >> 1, off = (tid & 1) * 64;
        const __half* srcp = &WT[(size_t)cr * 128 + off];
#pragma unroll
        for (int q = 0; q < 8; ++q)
            *(float4*)&Ws[cr][off + q * 8] = *(const float4*)&srcp[q * 8];
    }
    {
        int xr = tid >> 2, co = (tid & 3) * 32;
        int gr = row0 + xr;
        if constexpr (std::is_same<InT, float>::value) {
#pragma unroll
            for (int q = 0; q < 4; ++q) {
                float4 lo = make_float4(0.f, 0.f, 0.f, 0.f);
                float4 hi = make_float4(0.f, 0.f, 0.f, 0.f);
                if (gr < N) {
                    lo = *(const float4*)&X[(size_t)gr * 128 + co + q * 8];
                    hi = *(const float4*)&X[(size_t)gr * 128 + co + q * 8 + 4];
                }
                __align__(16) __half2 tmp[4];
                tmp[0] = __floats2half2_rn(lo.x, lo.y);
                tmp[1] = __floats2half2_rn(lo.z, lo.w);
                tmp[2] = __floats2half2_rn(hi.x, hi.y);
                tmp[3] = __floats2half2_rn(hi.z, hi.w);
                *(float4*)&Xs[xr][co + q * 8] = *(const float4*)tmp;
            }
        } else {
#pragma unroll
            for (int q = 0; q < 4; ++q) {
                float4 vz = make_float4(0.f, 0.f, 0.f, 0.f);
                if (gr < N)
                    vz = *(const float4*)&X[(size_t)gr * 128 + co + q * 8];
                *(float4*)&Xs[xr][co + q * 8] = vz;
            }
        }
    }
    __syncthreads();

    const int wid = tid >> 6;
    const int lane = tid & 63;
    const int lr = lane & 15, ks = lane >> 4;
    floatx4 acc[8];
#pragma unroll
    for (int t = 0; t < 8; ++t) acc[t] = (floatx4){0.f, 0.f, 0.f, 0.f};

#pragma unroll
    for (int kk = 0; kk < 4; ++kk) {
        half8 a = *(const half8*)&Xs[wid * 16 + lr][kk * 32 + ks * 8];
#pragma unroll
        for (int t = 0; t < 8; ++t) {
            half8 b = *(const half8*)&Ws[t * 16 + lr][kk * 32 + ks * 8];
            acc[t] = __builtin_amdgcn_mfma_f32_16x16x32_f16(a, b, acc[t], 0, 0, 0);
        }
    }
#pragma unroll
    for (int r = 0; r < 4; ++r) {
        int grow = row0 + wid * 16 + ks * 4 + r;
        if (grow < N) {
#pragma unroll
            for (int t = 0; t < 8; ++t)
                C[(size_t)grow * 128 + t * 16 + lr] = __float2half_rn(acc[t][r]);
        }
    }

    // fused al: thread t handles row t>>2, dim-quarter t&3 (32 dims)
    {
        const int r = tid >> 2, q = tid & 3;
        float ps = 0.f, pd = 0.f;
        const int dbase = q * 32;
#pragma unroll
        for (int d = 0; d < 32; ++d) {
            float xv = __half2float(Xs[r][dbase + d]);
            ps = fmaf(xv, wvs[dbase + d], ps);
            pd = fmaf(xv, wvd[dbase + d], pd);
        }
        ps += __shfl_xor(ps, 1); ps += __shfl_xor(ps, 2);
        pd += __shfl_xor(pd, 1); pd += __shfl_xor(pd, 2);
        int gr = row0 + r;
        if (q == 0 && gr < N) { al_s[gr] = ps; al_d[gr] = pd; }
    }
}

// ---- fused aggregate: weight phase in-kernel, 16 gathers in flight --------
template <typename OutT, bool RELU>
__global__ __launch_bounds__(256) void gat_aggregate_fused(
    const __half* __restrict__ hs, const float* __restrict__ al_s,
    const float* __restrict__ al_d, const int* __restrict__ row_ptr,
    const int* __restrict__ col, const float* __restrict__ bias,
    OutT* __restrict__ out, int N) {
    int node = (int)((blockIdx.x * 256u + threadIdx.x) >> 6);
    int lane = threadIdx.x & 63;
    if (node >= N) return;
    const int begin = row_ptr[node], end = row_ptr[node + 1];
    const float ald = al_d[node];
    const int d0 = lane * 2;

    float acc0 = 0.f, acc1 = 0.f, den = 0.f;
    for (int base = begin; base < end; base += 64) {
        const int cnt = min(64, end - base);
        int myidx = 0;
        float w = 0.f;
        if (lane < cnt) {
            myidx = col[base + lane];
            float l = al_s[myidx] + ald;
            l = (l >= 0.f) ? l : 0.2f * l;
            w = __expf(l);
        }
        float ws = w;
#pragma unroll
        for (int o = 32; o >= 1; o >>= 1) ws += __shfl_xor(ws, o);
        den += ws;

        for (int e = 0; e < cnt; e += 16) {
            __half2 v[16];
            float we[16];
#pragma unroll
            for (int j = 0; j < 16; ++j) {
                int s = __shfl(myidx, e + j);
                we[j] = __shfl(w, e + j);
                v[j] = *(const __half2*)&hs[((size_t)(unsigned)s << 7) + d0];
            }
#pragma unroll
            for (int j = 0; j < 16; ++j) {
                float2 f = __half22float2(v[j]);
                acc0 = fmaf(we[j], f.x, acc0);
                acc1 = fmaf(we[j], f.y, acc1);
            }
        }
    }
    const float rden = (den > 0.f) ? 1.f / den : 0.f;
    float o0 = acc0 * rden + bias[d0];
    float o1 = acc1 * rden + bias[d0 + 1];
    if (RELU) { o0 = fmaxf(o0, 0.f); o1 = fmaxf(o1, 0.f); }
    if constexpr (std::is_same<OutT, __half>::value) {
        *(__half2*)&out[(size_t)node * 128 + d0] = __floats2half2_rn(o0, o1);
    } else {
        *(float2*)&out[(size_t)node * 128 + d0] = make_float2(o0, o1);
    }
}

// ---------------------------------------------------------------------------
extern "C" void kernel_launch(void* const* d_in, const int* in_sizes, int n_in,
                              void* d_out, int out_size, void* d_ws,
                              size_t ws_size, hipStream_t stream) {
    const float* x    = (const float*)d_in[0];
    const int*  eidx  = (const int*)d_in[1];
    const float* W1s  = (const float*)d_in[2];
    const float* W1d  = (const float*)d_in[3];
    const float* a1s  = (const float*)d_in[4];
    const float* a1d  = (const float*)d_in[5];
    const float* b1   = (const float*)d_in[6];
    const float* W2s  = (const float*)d_in[7];
    const float* W2d  = (const float*)d_in[8];
    const float* a2s  = (const float*)d_in[9];
    const float* a2d  = (const float*)d_in[10];
    const float* b2   = (const float*)d_in[11];

    const int N = in_sizes[0] / 128;
    const int E = in_sizes[1] / 2;
    const int* src = eidx;
    const int* dst = eidx + E;

    const int NB   = (N + 255) >> BKT_SHIFT;
    const int NBLK = (E + EPB - 1) / EPB;

    char* p = (char*)d_ws;
    auto alloc = [&](size_t bytes) {
        char* r = p;
        p += (bytes + 255) & ~(size_t)255;
        return r;
    };
    __half* hsA   = (__half*)alloc((size_t)N * 128 * 2);
    __half* h1    = (__half*)alloc((size_t)N * 128 * 2);
    int*   row_ptr= (int*)alloc((size_t)(N + 1) * 4);
    int*   col    = (int*)alloc((size_t)E * 4);
    int*   bpack  = (int*)alloc((size_t)E * 4);
    int*   counts = (int*)alloc((size_t)NBLK * NB * 4);
    int*   totals = (int*)alloc(MAX_NB * 4);
    int*   bbase  = (int*)alloc(MAX_NB * 4);
    float* al_s   = (float*)alloc((size_t)N * 4);
    float* al_d   = (float*)alloc((size_t)N * 4);
    float* wv     = (float*)alloc(4 * 128 * 4);
    __half* wt1   = (__half*)alloc(128 * 128 * 2);
    __half* wt2   = (__half*)alloc(128 * 128 * 2);

    // ---- CSR build + prep (5 launches) ----
    bucket_count_prep_kernel<<<NBLK + 36, 256, 0, stream>>>(
        dst, counts, W1s, a1s, W1d, a1d, W2s, a2s, W2d, a2d, wt1, wt2, wv, E,
        NB, NBLK);
    bucket_prefix_kernel<<<NB, 256, 0, stream>>>(counts, totals, NBLK, NB);
    bucket_base_kernel<<<1, MAX_NB, 0, stream>>>(totals, bbase, NB);
    bucket_place_kernel<<<NBLK, 256, 0, stream>>>(src, dst, counts, bbase,
                                                  bpack, E, NB);
    bucket_csr_kernel<<<NB, 256, 0, stream>>>(bpack, bbase, row_ptr, col, N, E,
                                              NB);

    const int gemm_grid = (N + 63) / 64;
    const int wave_grid = (N + 3) / 4;

    // ---- layer 1 ----
    gemm_mfma_kernel<float><<<gemm_grid, 256, 0, stream>>>(
        x, wt1, hsA, wv + 0, wv + 128, al_s, al_d, N);
    gat_aggregate_fused<__half, true><<<wave_grid, 256, 0, stream>>>(
        hsA, al_s, al_d, row_ptr, col, b1, h1, N);

    // ---- layer 2 ----
    gemm_mfma_kernel<__half><<<gemm_grid, 256, 0, stream>>>(
        h1, wt2, hsA, wv + 256, wv + 384, al_s, al_d, N);
    gat_aggregate_fused<float, false><<<wave_grid, 256, 0, stream>>>(
        hsA, al_s, al_d, row_ptr, col, b2, (float*)d_out, N);
}